// Round 1
// baseline (267.198 us; speedup 1.0000x reference)
//
#include <hip/hip_runtime.h>
#include <hip/hip_fp16.h>

// B=4, T=2048, C=1024. Single-head causal attention, fp32 in/out.
// Internals fp16 (MFMA f32_16x16x32_f16), fp32 accum + fp32 softmax.
// R9: qkv_gemm ported to the m201-style 8-phase 256x256/BK=64/8-wave
// schedule: global_load_lds direct staging (linear LDS dest, pre-swizzled
// per-lane global source == the verified 0-conflict XOR chunk swizzle),
// counted s_waitcnt vmcnt(4) once per K-tile (never 0 mid-loop), raw
// s_barrier pairs per phase, s_setprio(1) around each 16-MFMA cluster.
// Old 2-barrier reg-staged core (measured ceiling ~680 TF) retained for
// scores/pv this round.

typedef __attribute__((ext_vector_type(8))) _Float16 half8;
typedef __attribute__((ext_vector_type(4))) _Float16 half4;
typedef __attribute__((ext_vector_type(4))) float f32x4;

// ---------------------------------------------------------------------------
// OLD NT-GEMM core (scores / pv), unchanged from R8. TM x TN tile, BK=64,
// 256 thr = WM*WN waves. LDS swizzle verified 0 conflicts.
// ---------------------------------------------------------------------------
template<int TM, int TN, int WM, int WN, bool SWAP>
__device__ __forceinline__ void gemm_nt_core(
    const _Float16* __restrict__ A, const _Float16* __restrict__ B,
    int lda, int ldb, int k0, int k1,
    _Float16* ldsA, _Float16* ldsB,      // TM*64, TN*64 halves
    f32x4 acc[TM / (WM * 16)][TN / (WN * 16)])
{
    constexpr int FM = TM / (WM * 16), FN = TN / (WN * 16);
    constexpr int NA = TM / 32, NB = TN / 32;   // 16B chunks per thread
    const int t    = threadIdx.x;
    const int lane = t & 63;
    const int w    = t >> 6;
    const int wm   = w % WM;
    const int wn   = w / WM;
    const int lr   = lane & 15;
    const int lq   = lane >> 4;

    const _Float16* ga[NA]; int loA[NA];
    const _Float16* gb[NB]; int loB[NB];
#pragma unroll
    for (int i = 0; i < NA; ++i) {
        int f = t + 256 * i;
        int r = f >> 3, c = (f & 7) ^ ((f >> 3) & 7);
        ga[i] = A + (size_t)r * lda + c * 8;
        loA[i] = f * 8;
    }
#pragma unroll
    for (int i = 0; i < NB; ++i) {
        int f = t + 256 * i;
        int r = f >> 3, c = (f & 7) ^ ((f >> 3) & 7);
        gb[i] = B + (size_t)r * ldb + c * 8;
        loB[i] = f * 8;
    }

    int offA[2][FM], offB[2][FN];
#pragma unroll
    for (int h = 0; h < 2; ++h) {
#pragma unroll
        for (int i = 0; i < FM; ++i) {
            int R = wm * (TM / WM) + i * 16 + lr;
            offA[h][i] = (8 * R + ((h * 4 + lq) ^ (R & 7))) * 8;
        }
#pragma unroll
        for (int i = 0; i < FN; ++i) {
            int R = wn * (TN / WN) + i * 16 + lr;
            offB[h][i] = (8 * R + ((h * 4 + lq) ^ (R & 7))) * 8;
        }
    }

    // prologue: tile k0 -> registers
    half8 va[NA], vb[NB];
#pragma unroll
    for (int i = 0; i < NA; ++i) va[i] = *(const half8*)(ga[i] + k0);
#pragma unroll
    for (int i = 0; i < NB; ++i) vb[i] = *(const half8*)(gb[i] + k0);

    for (int k = k0; k < k1; k += 64) {
        __syncthreads();               // prev iter's LDS readers done
#pragma unroll
        for (int i = 0; i < NA; ++i) *(half8*)(ldsA + loA[i]) = va[i];
#pragma unroll
        for (int i = 0; i < NB; ++i) *(half8*)(ldsB + loB[i]) = vb[i];
        if (k + 64 < k1) {             // issue next tile's loads; they fly
#pragma unroll                         // during this iter's compute phase
            for (int i = 0; i < NA; ++i) va[i] = *(const half8*)(ga[i] + k + 64);
#pragma unroll
            for (int i = 0; i < NB; ++i) vb[i] = *(const half8*)(gb[i] + k + 64);
        }
        __syncthreads();               // LDS writes visible

#pragma unroll
        for (int h = 0; h < 2; ++h) {
            half8 af[FM], bf[FN];
#pragma unroll
            for (int i = 0; i < FM; ++i) af[i] = *(const half8*)(ldsA + offA[h][i]);
#pragma unroll
            for (int i = 0; i < FN; ++i) bf[i] = *(const half8*)(ldsB + offB[h][i]);
#pragma unroll
            for (int mi = 0; mi < FM; ++mi)
#pragma unroll
                for (int ni = 0; ni < FN; ++ni) {
                    if constexpr (SWAP)
                        acc[mi][ni] = __builtin_amdgcn_mfma_f32_16x16x32_f16(
                            bf[ni], af[mi], acc[mi][ni], 0, 0, 0);
                    else
                        acc[mi][ni] = __builtin_amdgcn_mfma_f32_16x16x32_f16(
                            af[mi], bf[ni], acc[mi][ni], 0, 0, 0);
                }
        }
    }
}

// ---------------------------------------------------------------------------
// NEW 256x256 8-phase core (qkv). BK=64, 512 thr = 8 waves (2M x 4N),
// per-wave 128x64 output (FM=8, FN=4). LDS 128 KiB: A dbuf [0,64K),
// B dbuf [64K,128K); per buffer 2 halves of 128x64 halves each.
// Staging: global_load_lds dwordx4, linear LDS dest chunk f=t+512j,
// pre-swizzled global source (row=f>>3, colchunk=(f&7)^((f>>3)&7)).
// Fragment read (local row R, kq=kh*4+lq): chunk 8R + (kq^(R&7)).
// Pipeline per K-tile tau (4 phases):
//   p1: ds af[m0..3]+bf0[n0..1] | issue (tau+1)A1 -> buf^1 | 16 MFMA q00
//   p2: ds bf1[n2..3]           | issue (tau+1)B1 -> buf^1 | 16 MFMA q01
//   p3: ds af[m4..7]            | issue (tau+2)B0 -> buf    | 16 MFMA q11
//   p4:                         | issue (tau+2)A0 -> buf    | 16 MFMA q10
//       s_waitcnt vmcnt(4)   <- drains all of tile tau+1 (8 loads), keeps
//                               (tau+2)B0/A0 (4 loads) in flight.
// Every staged region's last ds_read is >=1 barrier before its issue phase.
// ---------------------------------------------------------------------------
__device__ __forceinline__ void gload_lds16(const void* g, void* l)
{
    __builtin_amdgcn_global_load_lds(
        (const __attribute__((address_space(1))) void*)g,
        (__attribute__((address_space(3))) void*)l, 16, 0, 0);
}

template<bool SWAP>
__device__ __forceinline__ void gemm_nt_256(
    const _Float16* __restrict__ A, const _Float16* __restrict__ B,
    const int lda, const int ldb, const int kTiles,   // kTiles even, >=2
    _Float16* lds, f32x4 acc[8][4])
{
    const int t    = threadIdx.x;
    const int lane = t & 63;
    const int w    = t >> 6;
    const int wm   = w & 1;
    const int wn   = w >> 1;
    const int lr   = lane & 15;
    const int lq   = lane >> 4;

    // staging source base: chunk f = t (rows 0..63); f+512 is +64 rows,
    // same colchunk since 64 % 8 == 0.
    const int r0 = t >> 3;
    const int c0 = (t & 7) ^ (r0 & 7);
    const _Float16* gA = A + (size_t)r0 * lda + c0 * 8;
    const _Float16* gB = B + (size_t)r0 * ldb + c0 * 8;

    char* ldsc = (char*)lds;
    char* stA = ldsc + w * 1024;           // + buf*32768 + h*16384 (+8192 j=1)
    char* stB = ldsc + 65536 + w * 1024;

    const int x0 = ((0 + lq) ^ (lr & 7)) * 16;   // kh=0 xor term
    const int x1 = ((4 + lq) ^ (lr & 7)) * 16;   // kh=1 xor term
    const char* rdA = ldsc + wm * 16384 + lr * 128;
    const char* rdB = ldsc + 65536 + (wn >> 1) * 16384 + (wn & 1) * 8192
                      + lr * 128;

    half8 af[4][2], bf0[2][2], bf1[2][2];

#define STGA(BUF, H, KOFF) do {                                               \
    const _Float16* _s = gA + (size_t)(H) * 128 * lda + (KOFF);               \
    char* _d = stA + (BUF) * 32768 + (H) * 16384;                             \
    gload_lds16(_s, _d);                                                      \
    gload_lds16(_s + (size_t)64 * lda, _d + 8192);                            \
} while (0)

#define STGB(BUF, H, KOFF) do {                                               \
    const _Float16* _s = gB + (size_t)(H) * 128 * ldb + (KOFF);               \
    char* _d = stB + (BUF) * 32768 + (H) * 16384;                             \
    gload_lds16(_s, _d);                                                      \
    gload_lds16(_s + (size_t)64 * ldb, _d + 8192);                            \
} while (0)

#define LDA_Q(BUF, MQ) do {                                                   \
    const char* _p = rdA + (BUF) * 32768 + (MQ) * 8192;                       \
    _Pragma("unroll")                                                         \
    for (int mi = 0; mi < 4; ++mi) {                                          \
        af[mi][0] = *(const half8*)(_p + mi * 2048 + x0);                     \
        af[mi][1] = *(const half8*)(_p + mi * 2048 + x1);                     \
    }                                                                         \
} while (0)

#define LDB_Q(DST, BUF, NQ) do {                                              \
    const char* _p = rdB + (BUF) * 32768 + (NQ) * 4096;                       \
    _Pragma("unroll")                                                         \
    for (int ni = 0; ni < 2; ++ni) {                                          \
        DST[ni][0] = *(const half8*)(_p + ni * 2048 + x0);                    \
        DST[ni][1] = *(const half8*)(_p + ni * 2048 + x1);                    \
    }                                                                         \
} while (0)

#define MFMA_Q(MQ, NQ, BSRC) do {                                             \
    _Pragma("unroll")                                                         \
    for (int mi = 0; mi < 4; ++mi)                                            \
    _Pragma("unroll")                                                         \
    for (int ni = 0; ni < 2; ++ni)                                            \
    _Pragma("unroll")                                                         \
    for (int kh = 0; kh < 2; ++kh) {                                          \
        if constexpr (SWAP)                                                   \
            acc[(MQ)*4+mi][(NQ)*2+ni] = __builtin_amdgcn_mfma_f32_16x16x32_f16(\
                BSRC[ni][kh], af[mi][kh], acc[(MQ)*4+mi][(NQ)*2+ni], 0, 0, 0);\
        else                                                                  \
            acc[(MQ)*4+mi][(NQ)*2+ni] = __builtin_amdgcn_mfma_f32_16x16x32_f16(\
                af[mi][kh], BSRC[ni][kh], acc[(MQ)*4+mi][(NQ)*2+ni], 0, 0, 0);\
    }                                                                         \
} while (0)

#define PH_PRE() do {                                                         \
    asm volatile("" ::: "memory");                                            \
    __builtin_amdgcn_s_barrier();                                             \
    asm volatile("s_waitcnt lgkmcnt(0)" ::: "memory");                        \
    __builtin_amdgcn_sched_barrier(0);                                        \
    __builtin_amdgcn_s_setprio(1);                                            \
} while (0)

#define PH_POST() do {                                                        \
    __builtin_amdgcn_s_setprio(0);                                            \
    __builtin_amdgcn_sched_barrier(0);                                        \
    __builtin_amdgcn_s_barrier();                                             \
    asm volatile("" ::: "memory");                                            \
} while (0)

#define KTILE(KT, BUF) do {                                                   \
    const int _k1 = ((KT) + 1) * 64, _k2 = ((KT) + 2) * 64;                   \
    const bool _s1 = (KT) + 1 < kTiles, _s2 = (KT) + 2 < kTiles;              \
    /* p1 */                                                                  \
    LDA_Q(BUF, 0);                                                            \
    LDB_Q(bf0, BUF, 0);                                                       \
    if (_s1) STGA((BUF) ^ 1, 1, _k1);                                         \
    PH_PRE(); MFMA_Q(0, 0, bf0); PH_POST();                                   \
    /* p2 */                                                                  \
    LDB_Q(bf1, BUF, 1);                                                       \
    if (_s1) STGB((BUF) ^ 1, 1, _k1);                                         \
    PH_PRE(); MFMA_Q(0, 1, bf1); PH_POST();                                   \
    /* p3 */                                                                  \
    LDA_Q(BUF, 1);                                                            \
    if (_s2) STGB(BUF, 0, _k2);                                               \
    PH_PRE(); MFMA_Q(1, 1, bf1); PH_POST();                                   \
    /* p4 (no ds_reads; af/bf0 still live) */                                 \
    if (_s2) STGA(BUF, 0, _k2);                                               \
    asm volatile("" ::: "memory");                                            \
    __builtin_amdgcn_s_barrier();                                             \
    __builtin_amdgcn_s_setprio(1);                                            \
    MFMA_Q(1, 0, bf0);                                                        \
    __builtin_amdgcn_s_setprio(0);                                            \
    if (_s2) asm volatile("s_waitcnt vmcnt(4)" ::: "memory");                 \
    else     asm volatile("s_waitcnt vmcnt(0)" ::: "memory");                 \
    __builtin_amdgcn_sched_barrier(0);                                        \
    __builtin_amdgcn_s_barrier();                                             \
    asm volatile("" ::: "memory");                                            \
} while (0)

    // prologue: tile0 fully, then tile1 B0/A0; vmcnt(4) drains tile0 and
    // leaves tile1's first 2 half-tiles in flight.
    STGA(0, 0, 0); STGA(0, 1, 0); STGB(0, 0, 0); STGB(0, 1, 0);
    if (kTiles > 1) { STGB(1, 0, 64); STGA(1, 0, 64); }
    if (kTiles > 1) asm volatile("s_waitcnt vmcnt(4)" ::: "memory");
    else            asm volatile("s_waitcnt vmcnt(0)" ::: "memory");
    __builtin_amdgcn_sched_barrier(0);
    __builtin_amdgcn_s_barrier();
    asm volatile("" ::: "memory");

#pragma unroll 1
    for (int kt = 0; kt < kTiles; kt += 2) {
        KTILE(kt, 0);
        KTILE(kt + 1, 1);
    }

#undef STGA
#undef STGB
#undef LDA_Q
#undef LDB_Q
#undef MFMA_Q
#undef PH_PRE
#undef PH_POST
#undef KTILE
}

// ---------------------------------------------------------------------------
__global__ __launch_bounds__(256) void f32tof16_k(
    const float* __restrict__ in, _Float16* __restrict__ out, int n)
{
    int i = (blockIdx.x * 256 + threadIdx.x) * 4;
    if (i < n) {
        float4 f = *(const float4*)(in + i);
        half4 h = { (_Float16)f.x, (_Float16)f.y, (_Float16)f.z, (_Float16)f.w };
        *(half4*)(out + i) = h;
    }
}

__global__ __launch_bounds__(256) void wconv_k(
    const float* __restrict__ Wq, const float* __restrict__ Wk,
    const float* __restrict__ Wv, _Float16* __restrict__ out)
{
    const float* src = (blockIdx.y == 0) ? Wq : (blockIdx.y == 1) ? Wk : Wv;
    int i = (blockIdx.x * 256 + threadIdx.x) * 4;
    float4 f = *(const float4*)(src + i);
    half4 h = { (_Float16)f.x, (_Float16)f.y, (_Float16)f.z, (_Float16)f.w };
    *(half4*)(out + (size_t)blockIdx.y * 1024 * 1024 + i) = h;
}

// ---------------------------------------------------------------------------
// Fused QKV on the 8-phase 256^2 core: grid (32,4,3) = 384 blocks x 512 thr.
// z=0 Q[t][d], z=1 K[s][d] (SWAP epilogue, half4 along d); z=2 Vt[b][d][t]
// (non-SWAP, half4 along t). Fragment->element maps identical to the
// verified 128^2 epilogues, only wave strides changed (wm*128, mi 0..7).
// ---------------------------------------------------------------------------
__global__ __launch_bounds__(512, 2) void qkv_gemm256_k(
    const _Float16* __restrict__ xh, const _Float16* __restrict__ Wh,
    _Float16* __restrict__ Q, _Float16* __restrict__ K,
    _Float16* __restrict__ Vt)
{
    __shared__ __align__(16) _Float16 lds[65536];   // 128 KiB
    const int tileM = blockIdx.x * 256;
    const int tileN = blockIdx.y * 256;
    const int z     = blockIdx.z;
    const _Float16* W = Wh + (size_t)z * 1024 * 1024;

    const int lane = threadIdx.x & 63;
    const int w    = threadIdx.x >> 6;
    const int wm = w & 1, wn = w >> 1;
    const int lr = lane & 15, lq = lane >> 4;

    f32x4 acc[8][4] = {};
    if (z == 2) {
        gemm_nt_256<false>(xh + (size_t)tileM * 1024, W + (size_t)tileN * 1024,
                           1024, 1024, 16, lds, acc);
#pragma unroll
        for (int mi = 0; mi < 8; ++mi)
#pragma unroll
            for (int ni = 0; ni < 4; ++ni) {
                int m0 = tileM + wm * 128 + mi * 16 + lq * 4;
                int n  = tileN + wn * 64 + ni * 16 + lr;
                int b = m0 >> 11, tt = m0 & 2047;
                half4 h = { (_Float16)acc[mi][ni][0], (_Float16)acc[mi][ni][1],
                            (_Float16)acc[mi][ni][2], (_Float16)acc[mi][ni][3] };
                *(half4*)(Vt + (size_t)b * 2048 * 1024 + (size_t)n * 2048 + tt) = h;
            }
    } else {
        gemm_nt_256<true>(xh + (size_t)tileM * 1024, W + (size_t)tileN * 1024,
                          1024, 1024, 16, lds, acc);
        _Float16* O = (z == 0) ? Q : K;
#pragma unroll
        for (int mi = 0; mi < 8; ++mi)
#pragma unroll
            for (int ni = 0; ni < 4; ++ni) {
                int tt = tileM + wm * 128 + mi * 16 + lr;
                int d0 = tileN + wn * 64 + ni * 16 + lq * 4;
                half4 h = { (_Float16)acc[mi][ni][0], (_Float16)acc[mi][ni][1],
                            (_Float16)acc[mi][ni][2], (_Float16)acc[mi][ni][3] };
                *(half4*)(O + (size_t)tt * 1024 + d0) = h;
            }
    }
}

// ---------------------------------------------------------------------------
// Scores (fp16): 128x128 tiles, grid (16,16,4), early-return above diagonal.
// Swapped MFMA -> half4 along s, causal mask to 0 in-tile.
// ---------------------------------------------------------------------------
__global__ __launch_bounds__(256) void scores_gemm_k(
    const _Float16* __restrict__ Q, const _Float16* __restrict__ K,
    _Float16* __restrict__ S)
{
    const int ti = blockIdx.x, si = blockIdx.y;
    if (si > ti) return;                     // fully above diagonal
    const int tileT = ti * 128, tileS = si * 128, b = blockIdx.z;

    __shared__ __align__(16) _Float16 ldsA[128 * 64];
    __shared__ __align__(16) _Float16 ldsB[128 * 64];
    f32x4 acc[4][4] = {};
    gemm_nt_core<128, 128, 2, 2, true>(
        Q + (size_t)b * 2048 * 1024 + (size_t)tileT * 1024,
        K + (size_t)b * 2048 * 1024 + (size_t)tileS * 1024,
        1024, 1024, 0, 1024, ldsA, ldsB, acc);

    const int lane = threadIdx.x & 63;
    const int w    = threadIdx.x >> 6;
    const int wm = w & 1, wn = w >> 1;
    const int lr = lane & 15, lq = lane >> 4;
    const float scale = 0.03125f;  // 1024^-0.5

#pragma unroll
    for (int mi = 0; mi < 4; ++mi)
#pragma unroll
        for (int ni = 0; ni < 4; ++ni) {
            int tt = tileT + wm * 64 + mi * 16 + lr;
            int s0 = tileS + wn * 64 + ni * 16 + lq * 4;
            half4 h;
#pragma unroll
            for (int r = 0; r < 4; ++r)
                h[r] = (s0 + r <= tt) ? (_Float16)(acc[mi][ni][r] * scale)
                                      : (_Float16)0.f;
            *(half4*)(S + ((size_t)b * 2048 + tt) * 2048 + s0) = h;
        }
}

// ---------------------------------------------------------------------------
// Softmax: one wave per row, half8 loads, 64-lane shuffle reduce, no LDS,
// no block barriers. In-tile s>t already 0 from scores; PV never reads
// beyond its kEnd.
// ---------------------------------------------------------------------------
__global__ __launch_bounds__(256) void softmax_k(_Float16* __restrict__ S)
{
    const int w    = threadIdx.x >> 6;
    const int lane = threadIdx.x & 63;
    const int t    = blockIdx.x * 4 + w;
    const int b    = blockIdx.y;
    _Float16* row = S + ((size_t)b * 2048 + t) * 2048;

    float x[32];
    float mx = -1e30f;
#pragma unroll
    for (int j = 0; j < 4; ++j) {
        half8 h = *(const half8*)(row + j * 512 + lane * 8);
#pragma unroll
        for (int e = 0; e < 8; ++e) {
            int s = j * 512 + lane * 8 + e;
            float f = (s <= t) ? (float)h[e] : -1e30f;
            x[j * 8 + e] = f;
            mx = fmaxf(mx, f);
        }
    }
#pragma unroll
    for (int o = 32; o > 0; o >>= 1) mx = fmaxf(mx, __shfl_xor(mx, o));

    float sum = 0.f;
#pragma unroll
    for (int i = 0; i < 32; ++i) {
        float e = __expf(x[i] - mx);   // masked: exp(-huge) -> 0
        x[i] = e;
        sum += e;
    }
#pragma unroll
    for (int o = 32; o > 0; o >>= 1) sum += __shfl_xor(sum, o);
    const float inv = 1.0f / sum;

#pragma unroll
    for (int j = 0; j < 4; ++j) {
        half8 p;
#pragma unroll
        for (int e = 0; e < 8; ++e) p[e] = (_Float16)(x[j * 8 + e] * inv);
        *(half8*)(row + j * 512 + lane * 8) = p;
    }
}

// ---------------------------------------------------------------------------
// PV: 128(t) x 64(d) tiles -> grid (16,16,4) = 1024 blocks, kEnd = tileT+128.
// Longest t-tiles first. Swapped MFMA -> float4 along d.
// ---------------------------------------------------------------------------
__global__ __launch_bounds__(256) void pv_gemm_k(
    const _Float16* __restrict__ P, const _Float16* __restrict__ Vt,
    float* __restrict__ out)
{
    __shared__ __align__(16) _Float16 ldsA[128 * 64];
    __shared__ __align__(16) _Float16 ldsB[64 * 64];
    const int tileT = (15 - blockIdx.x) * 128;   // longest-first
    const int tileD = blockIdx.y * 64;
    const int b     = blockIdx.z;
    const int kEnd  = tileT + 128;

    f32x4 acc[4][2] = {};
    gemm_nt_core<128, 64, 2, 2, true>(
        P + ((size_t)b * 2048 + tileT) * 2048,
        Vt + (size_t)b * 1024 * 2048 + (size_t)tileD * 2048,
        2048, 2048, 0, kEnd, ldsA, ldsB, acc);

    const int lane = threadIdx.x & 63;
    const int w    = threadIdx.x >> 6;
    const int wm = w & 1, wn = w >> 1;
    const int lr = lane & 15, lq = lane >> 4;

#pragma unroll
    for (int mi = 0; mi < 4; ++mi)
#pragma unroll
        for (int ni = 0; ni < 2; ++ni) {
            int tt = tileT + wm * 64 + mi * 16 + lr;
            int d0 = tileD + wn * 32 + ni * 16 + lq * 4;
            *(f32x4*)(out + ((size_t)b * 2048 + tt) * 1024 + d0) = acc[mi][ni];
        }
}

// ---------------------------------------------------------------------------
extern "C" void kernel_launch(void* const* d_in, const int* in_sizes, int n_in,
                              void* d_out, int out_size, void* d_ws, size_t ws_size,
                              hipStream_t stream)
{
    const float* x  = (const float*)d_in[0];
    const float* Wq = (const float*)d_in[1];
    const float* Wk = (const float*)d_in[2];
    const float* Wv = (const float*)d_in[3];
    float* out = (float*)d_out;

    char* ws = (char*)d_ws;
    // layout (MB): xh 0..16 | Wh 16..22 | Q 22..38 | K 38..54 | Vt 54..70 |
    // S16 70..102 (P aliases S).  Total 102 MB.
    _Float16* xh = (_Float16*)(ws);
    _Float16* Wh = (_Float16*)(ws + (16u << 20));
    _Float16* Qh = (_Float16*)(ws + (22u << 20));
    _Float16* Kh = (_Float16*)(ws + (38u << 20));
    _Float16* Vt = (_Float16*)(ws + (54u << 20));
    _Float16* S  = (_Float16*)(ws + (70u << 20));

    f32tof16_k<<<8192, 256, 0, stream>>>(x, xh, 4 * 2048 * 1024);
    wconv_k<<<dim3(1024, 3), 256, 0, stream>>>(Wq, Wk, Wv, Wh);

    qkv_gemm256_k<<<dim3(32, 4, 3), 512, 0, stream>>>(xh, Wh, Qh, Kh, Vt);

    scores_gemm_k<<<dim3(16, 16, 4), 256, 0, stream>>>(Qh, Kh, S);
    softmax_k<<<dim3(512, 4), 256, 0, stream>>>(S);
    pv_gemm_k<<<dim3(16, 16, 4), 256, 0, stream>>>(S, Vt, out);
}

// Round 2
// 249.030 us; speedup vs baseline: 1.0730x; 1.0730x over previous
//
#include <hip/hip_runtime.h>
#include <hip/hip_fp16.h>

// B=4, T=2048, C=1024. Single-head causal attention, fp32 in/out.
// Internals fp16 (MFMA f32_16x16x32_f16), fp32 accum + fp32 softmax.
// R10: qkv on a 256x128-tile counted-vmcnt core: 768 blocks = EXACTLY 3.0
// rounds on 256 CUs (R9's 384-block 256^2 grid packed at 75% -> MfmaUtil
// capped at ~28%). Same verified phase template (barrier/lgkm/MFMA/barrier,
// vmcnt(4) once per K-tile, never 0 mid-loop), geometry remapped:
// 8 waves 4Mx2N, per-wave 64x64 (FM=FN=4), 2 phases/K-tile x 16 MFMA,
// LDS 96 KiB. Softmax now skips fully-masked 512-chunks (j <= t>>9).

typedef __attribute__((ext_vector_type(8))) _Float16 half8;
typedef __attribute__((ext_vector_type(4))) _Float16 half4;
typedef __attribute__((ext_vector_type(4))) float f32x4;

// ---------------------------------------------------------------------------
// OLD NT-GEMM core (scores / pv), unchanged. TM x TN tile, BK=64,
// 256 thr = WM*WN waves. LDS swizzle verified 0 conflicts.
// ---------------------------------------------------------------------------
template<int TM, int TN, int WM, int WN, bool SWAP>
__device__ __forceinline__ void gemm_nt_core(
    const _Float16* __restrict__ A, const _Float16* __restrict__ B,
    int lda, int ldb, int k0, int k1,
    _Float16* ldsA, _Float16* ldsB,      // TM*64, TN*64 halves
    f32x4 acc[TM / (WM * 16)][TN / (WN * 16)])
{
    constexpr int FM = TM / (WM * 16), FN = TN / (WN * 16);
    constexpr int NA = TM / 32, NB = TN / 32;   // 16B chunks per thread
    const int t    = threadIdx.x;
    const int lane = t & 63;
    const int w    = t >> 6;
    const int wm   = w % WM;
    const int wn   = w / WM;
    const int lr   = lane & 15;
    const int lq   = lane >> 4;

    const _Float16* ga[NA]; int loA[NA];
    const _Float16* gb[NB]; int loB[NB];
#pragma unroll
    for (int i = 0; i < NA; ++i) {
        int f = t + 256 * i;
        int r = f >> 3, c = (f & 7) ^ ((f >> 3) & 7);
        ga[i] = A + (size_t)r * lda + c * 8;
        loA[i] = f * 8;
    }
#pragma unroll
    for (int i = 0; i < NB; ++i) {
        int f = t + 256 * i;
        int r = f >> 3, c = (f & 7) ^ ((f >> 3) & 7);
        gb[i] = B + (size_t)r * ldb + c * 8;
        loB[i] = f * 8;
    }

    int offA[2][FM], offB[2][FN];
#pragma unroll
    for (int h = 0; h < 2; ++h) {
#pragma unroll
        for (int i = 0; i < FM; ++i) {
            int R = wm * (TM / WM) + i * 16 + lr;
            offA[h][i] = (8 * R + ((h * 4 + lq) ^ (R & 7))) * 8;
        }
#pragma unroll
        for (int i = 0; i < FN; ++i) {
            int R = wn * (TN / WN) + i * 16 + lr;
            offB[h][i] = (8 * R + ((h * 4 + lq) ^ (R & 7))) * 8;
        }
    }

    // prologue: tile k0 -> registers
    half8 va[NA], vb[NB];
#pragma unroll
    for (int i = 0; i < NA; ++i) va[i] = *(const half8*)(ga[i] + k0);
#pragma unroll
    for (int i = 0; i < NB; ++i) vb[i] = *(const half8*)(gb[i] + k0);

    for (int k = k0; k < k1; k += 64) {
        __syncthreads();               // prev iter's LDS readers done
#pragma unroll
        for (int i = 0; i < NA; ++i) *(half8*)(ldsA + loA[i]) = va[i];
#pragma unroll
        for (int i = 0; i < NB; ++i) *(half8*)(ldsB + loB[i]) = vb[i];
        if (k + 64 < k1) {             // issue next tile's loads; they fly
#pragma unroll                         // during this iter's compute phase
            for (int i = 0; i < NA; ++i) va[i] = *(const half8*)(ga[i] + k + 64);
#pragma unroll
            for (int i = 0; i < NB; ++i) vb[i] = *(const half8*)(gb[i] + k + 64);
        }
        __syncthreads();               // LDS writes visible

#pragma unroll
        for (int h = 0; h < 2; ++h) {
            half8 af[FM], bf[FN];
#pragma unroll
            for (int i = 0; i < FM; ++i) af[i] = *(const half8*)(ldsA + offA[h][i]);
#pragma unroll
            for (int i = 0; i < FN; ++i) bf[i] = *(const half8*)(ldsB + offB[h][i]);
#pragma unroll
            for (int mi = 0; mi < FM; ++mi)
#pragma unroll
                for (int ni = 0; ni < FN; ++ni) {
                    if constexpr (SWAP)
                        acc[mi][ni] = __builtin_amdgcn_mfma_f32_16x16x32_f16(
                            bf[ni], af[mi], acc[mi][ni], 0, 0, 0);
                    else
                        acc[mi][ni] = __builtin_amdgcn_mfma_f32_16x16x32_f16(
                            af[mi], bf[ni], acc[mi][ni], 0, 0, 0);
                }
        }
    }
}

// ---------------------------------------------------------------------------
// 256x128 counted-vmcnt core (qkv). BK=64, 512 thr = 8 waves (4M x 2N),
// per-wave 64x64 (FM=FN=4). LDS 96 KiB: A dbuf [0,64K) (BUF*32K, 4 slots
// of 8K = 64 rows), B dbuf [64K,96K) (BUF*16K, 2 slots of 8K).
// Staging: global_load_lds dwordx4, linear LDS dest (chunk f = t),
// pre-swizzled global source (row=t>>3, colchunk=(t&7)^((t>>3)&7)).
// Fragment read (slot-local row R, kq=kh*4+lq): byte R*128 + (kq^(R&7))*16.
// Per K-tile tau (2 phases):
//   ph1: ds af[all 8] + bf01[4] | stage (tau+1)B0,B1 -> buf^1 |
//        barrier; lgkm0; 16 MFMA (n-half 0); barrier
//   ph2: ds bf23[4]             | stage (tau+2)A0..A3 -> buf   |
//        barrier; lgkm0; 16 MFMA (n-half 1); vmcnt(4); barrier
// vmcnt(4) drains tile tau+1 fully (A issued ph2(tau-1), B issued ph1(tau)),
// keeps (tau+2)A's 4 loads in flight. A-slots of buf are stage-safe at ph2
// (fully read at ph1's lgkm0); B-slots of buf^1 safe any phase (last read
// >= 2 barriers prior). Never vmcnt(0) mid-loop.
// ---------------------------------------------------------------------------
__device__ __forceinline__ void gload_lds16(const void* g, void* l)
{
    __builtin_amdgcn_global_load_lds(
        (const __attribute__((address_space(1))) void*)g,
        (__attribute__((address_space(3))) void*)l, 16, 0, 0);
}

template<bool SWAP>
__device__ __forceinline__ void gemm_nt_256x128(
    const _Float16* __restrict__ A, const _Float16* __restrict__ B,
    const int lda, const int ldb, const int kTiles,   // kTiles even, >= 4
    _Float16* lds, f32x4 acc[4][4])
{
    const int t    = threadIdx.x;
    const int lane = t & 63;
    const int w    = t >> 6;
    const int wm   = w & 3;          // M quarter (64 rows)
    const int wn   = w >> 2;         // N half (64 cols)
    const int lr   = lane & 15;
    const int lq   = lane >> 4;

    const int r0 = t >> 3;                       // 0..63 within a slot
    const int c0 = (t & 7) ^ (r0 & 7);
    const _Float16* gA = A + (size_t)r0 * lda + c0 * 8;
    const _Float16* gB = B + (size_t)r0 * ldb + c0 * 8;

    char* ldsc = (char*)lds;
    char* stA = ldsc + w * 1024;              // + BUF*32768 + slot*8192
    char* stB = ldsc + 65536 + w * 1024;      // + BUF*16384 + slot*8192

    const int x0 = ((0 + lq) ^ (lr & 7)) * 16;
    const int x1 = ((4 + lq) ^ (lr & 7)) * 16;
    const char* rdA = ldsc + wm * 8192 + lr * 128;           // + BUF*32768 + mi*2048
    const char* rdB = ldsc + 65536 + wn * 8192 + lr * 128;   // + BUF*16384 + ni*2048

    half8 af[4][2], bf01[2][2], bf23[2][2];

#define STGA1(BUF, S, KOFF)                                                   \
    gload_lds16(gA + (size_t)(S) * 64 * lda + (KOFF),                         \
                stA + (BUF) * 32768 + (S) * 8192)

#define STGB1(BUF, S, KOFF)                                                   \
    gload_lds16(gB + (size_t)(S) * 64 * ldb + (KOFF),                         \
                stB + (BUF) * 16384 + (S) * 8192)

#define LDA_ALL(BUF) do {                                                     \
    const char* _p = rdA + (BUF) * 32768;                                     \
    _Pragma("unroll")                                                         \
    for (int mi = 0; mi < 4; ++mi) {                                          \
        af[mi][0] = *(const half8*)(_p + mi * 2048 + x0);                     \
        af[mi][1] = *(const half8*)(_p + mi * 2048 + x1);                     \
    }                                                                         \
} while (0)

#define LDB_H(DST, BUF, NQ) do {                                              \
    const char* _p = rdB + (BUF) * 16384 + (NQ) * 4096;                       \
    _Pragma("unroll")                                                         \
    for (int ni = 0; ni < 2; ++ni) {                                          \
        DST[ni][0] = *(const half8*)(_p + ni * 2048 + x0);                    \
        DST[ni][1] = *(const half8*)(_p + ni * 2048 + x1);                    \
    }                                                                         \
} while (0)

#define MFMA_NH(NQ, BSRC) do {                                                \
    _Pragma("unroll")                                                         \
    for (int mi = 0; mi < 4; ++mi)                                            \
    _Pragma("unroll")                                                         \
    for (int ni = 0; ni < 2; ++ni)                                            \
    _Pragma("unroll")                                                         \
    for (int kh = 0; kh < 2; ++kh) {                                          \
        if constexpr (SWAP)                                                   \
            acc[mi][(NQ)*2+ni] = __builtin_amdgcn_mfma_f32_16x16x32_f16(      \
                BSRC[ni][kh], af[mi][kh], acc[mi][(NQ)*2+ni], 0, 0, 0);       \
        else                                                                  \
            acc[mi][(NQ)*2+ni] = __builtin_amdgcn_mfma_f32_16x16x32_f16(      \
                af[mi][kh], BSRC[ni][kh], acc[mi][(NQ)*2+ni], 0, 0, 0);       \
    }                                                                         \
} while (0)

#define PH_PRE() do {                                                         \
    asm volatile("" ::: "memory");                                            \
    __builtin_amdgcn_s_barrier();                                             \
    asm volatile("s_waitcnt lgkmcnt(0)" ::: "memory");                        \
    __builtin_amdgcn_sched_barrier(0);                                        \
    __builtin_amdgcn_s_setprio(1);                                            \
} while (0)

#define PH_POST() do {                                                        \
    __builtin_amdgcn_s_setprio(0);                                            \
    __builtin_amdgcn_sched_barrier(0);                                        \
    __builtin_amdgcn_s_barrier();                                             \
    asm volatile("" ::: "memory");                                            \
} while (0)

#define KTILE(KT, BUF) do {                                                   \
    const int _k1 = ((KT) + 1) * 64, _k2 = ((KT) + 2) * 64;                   \
    const bool _s1 = (KT) + 1 < kTiles, _s2 = (KT) + 2 < kTiles;              \
    /* ph1 */                                                                 \
    LDA_ALL(BUF);                                                             \
    LDB_H(bf01, BUF, 0);                                                      \
    if (_s1) { STGB1((BUF) ^ 1, 0, _k1); STGB1((BUF) ^ 1, 1, _k1); }          \
    PH_PRE(); MFMA_NH(0, bf01); PH_POST();                                    \
    /* ph2 */                                                                 \
    LDB_H(bf23, BUF, 1);                                                      \
    if (_s2) { STGA1(BUF, 0, _k2); STGA1(BUF, 1, _k2);                        \
               STGA1(BUF, 2, _k2); STGA1(BUF, 3, _k2); }                      \
    asm volatile("" ::: "memory");                                            \
    __builtin_amdgcn_s_barrier();                                             \
    asm volatile("s_waitcnt lgkmcnt(0)" ::: "memory");                        \
    __builtin_amdgcn_sched_barrier(0);                                        \
    __builtin_amdgcn_s_setprio(1);                                            \
    MFMA_NH(1, bf23);                                                         \
    __builtin_amdgcn_s_setprio(0);                                            \
    if (_s2) asm volatile("s_waitcnt vmcnt(4)" ::: "memory");                 \
    else     asm volatile("s_waitcnt vmcnt(0)" ::: "memory");                 \
    __builtin_amdgcn_sched_barrier(0);                                        \
    __builtin_amdgcn_s_barrier();                                             \
    asm volatile("" ::: "memory");                                            \
} while (0)

    // prologue: tile0 fully (6 loads), then tile1's A (4 loads);
    // vmcnt(4) drains tile0, keeps tile1's A in flight (its B arrives at
    // ph1(0)) — identical steady-state invariant as the loop body.
    STGA1(0, 0, 0); STGA1(0, 1, 0); STGA1(0, 2, 0); STGA1(0, 3, 0);
    STGB1(0, 0, 0); STGB1(0, 1, 0);
    if (kTiles > 1) { STGA1(1, 0, 64); STGA1(1, 1, 64);
                      STGA1(1, 2, 64); STGA1(1, 3, 64); }
    if (kTiles > 1) asm volatile("s_waitcnt vmcnt(4)" ::: "memory");
    else            asm volatile("s_waitcnt vmcnt(0)" ::: "memory");
    __builtin_amdgcn_sched_barrier(0);
    __builtin_amdgcn_s_barrier();
    asm volatile("" ::: "memory");

#pragma unroll 1
    for (int kt = 0; kt < kTiles; kt += 2) {
        KTILE(kt, 0);
        KTILE(kt + 1, 1);
    }

#undef STGA1
#undef STGB1
#undef LDA_ALL
#undef LDB_H
#undef MFMA_NH
#undef PH_PRE
#undef PH_POST
#undef KTILE
}

// ---------------------------------------------------------------------------
__global__ __launch_bounds__(256) void f32tof16_k(
    const float* __restrict__ in, _Float16* __restrict__ out, int n)
{
    int i = (blockIdx.x * 256 + threadIdx.x) * 4;
    if (i < n) {
        float4 f = *(const float4*)(in + i);
        half4 h = { (_Float16)f.x, (_Float16)f.y, (_Float16)f.z, (_Float16)f.w };
        *(half4*)(out + i) = h;
    }
}

__global__ __launch_bounds__(256) void wconv_k(
    const float* __restrict__ Wq, const float* __restrict__ Wk,
    const float* __restrict__ Wv, _Float16* __restrict__ out)
{
    const float* src = (blockIdx.y == 0) ? Wq : (blockIdx.y == 1) ? Wk : Wv;
    int i = (blockIdx.x * 256 + threadIdx.x) * 4;
    float4 f = *(const float4*)(src + i);
    half4 h = { (_Float16)f.x, (_Float16)f.y, (_Float16)f.z, (_Float16)f.w };
    *(half4*)(out + (size_t)blockIdx.y * 1024 * 1024 + i) = h;
}

// ---------------------------------------------------------------------------
// Fused QKV on the 256x128 core: grid (32,8,3) = 768 blocks = 3.0 exact
// rounds on 256 CUs. z=0 Q[t][d], z=1 K[s][d] (SWAP, half4 along d);
// z=2 Vt[b][d][t] (non-SWAP, half4 along t). Wave map: wm=w&3 (64 rows),
// wn=w>>2 (64 cols).
// ---------------------------------------------------------------------------
__global__ __launch_bounds__(512, 2) void qkv_gemm256_k(
    const _Float16* __restrict__ xh, const _Float16* __restrict__ Wh,
    _Float16* __restrict__ Q, _Float16* __restrict__ K,
    _Float16* __restrict__ Vt)
{
    __shared__ __align__(16) _Float16 lds[49152];   // 96 KiB
    const int tileM = blockIdx.x * 256;
    const int tileN = blockIdx.y * 128;
    const int z     = blockIdx.z;
    const _Float16* W = Wh + (size_t)z * 1024 * 1024;

    const int lane = threadIdx.x & 63;
    const int w    = threadIdx.x >> 6;
    const int wm = w & 3, wn = w >> 2;
    const int lr = lane & 15, lq = lane >> 4;

    f32x4 acc[4][4] = {};
    if (z == 2) {
        gemm_nt_256x128<false>(xh + (size_t)tileM * 1024,
                               W + (size_t)tileN * 1024,
                               1024, 1024, 16, lds, acc);
#pragma unroll
        for (int mi = 0; mi < 4; ++mi)
#pragma unroll
            for (int ni = 0; ni < 4; ++ni) {
                int m0 = tileM + wm * 64 + mi * 16 + lq * 4;
                int n  = tileN + wn * 64 + ni * 16 + lr;
                int b = m0 >> 11, tt = m0 & 2047;
                half4 h = { (_Float16)acc[mi][ni][0], (_Float16)acc[mi][ni][1],
                            (_Float16)acc[mi][ni][2], (_Float16)acc[mi][ni][3] };
                *(half4*)(Vt + (size_t)b * 2048 * 1024 + (size_t)n * 2048 + tt) = h;
            }
    } else {
        gemm_nt_256x128<true>(xh + (size_t)tileM * 1024,
                              W + (size_t)tileN * 1024,
                              1024, 1024, 16, lds, acc);
        _Float16* O = (z == 0) ? Q : K;
#pragma unroll
        for (int mi = 0; mi < 4; ++mi)
#pragma unroll
            for (int ni = 0; ni < 4; ++ni) {
                int tt = tileM + wm * 64 + mi * 16 + lr;
                int d0 = tileN + wn * 64 + ni * 16 + lq * 4;
                half4 h = { (_Float16)acc[mi][ni][0], (_Float16)acc[mi][ni][1],
                            (_Float16)acc[mi][ni][2], (_Float16)acc[mi][ni][3] };
                *(half4*)(O + (size_t)tt * 1024 + d0) = h;
            }
    }
}

// ---------------------------------------------------------------------------
// Scores (fp16): 128x128 tiles, grid (16,16,4), early-return above diagonal.
// Swapped MFMA -> half4 along s, causal mask to 0 in-tile.
// ---------------------------------------------------------------------------
__global__ __launch_bounds__(256) void scores_gemm_k(
    const _Float16* __restrict__ Q, const _Float16* __restrict__ K,
    _Float16* __restrict__ S)
{
    const int ti = blockIdx.x, si = blockIdx.y;
    if (si > ti) return;                     // fully above diagonal
    const int tileT = ti * 128, tileS = si * 128, b = blockIdx.z;

    __shared__ __align__(16) _Float16 ldsA[128 * 64];
    __shared__ __align__(16) _Float16 ldsB[128 * 64];
    f32x4 acc[4][4] = {};
    gemm_nt_core<128, 128, 2, 2, true>(
        Q + (size_t)b * 2048 * 1024 + (size_t)tileT * 1024,
        K + (size_t)b * 2048 * 1024 + (size_t)tileS * 1024,
        1024, 1024, 0, 1024, ldsA, ldsB, acc);

    const int lane = threadIdx.x & 63;
    const int w    = threadIdx.x >> 6;
    const int wm = w & 1, wn = w >> 1;
    const int lr = lane & 15, lq = lane >> 4;
    const float scale = 0.03125f;  // 1024^-0.5

#pragma unroll
    for (int mi = 0; mi < 4; ++mi)
#pragma unroll
        for (int ni = 0; ni < 4; ++ni) {
            int tt = tileT + wm * 64 + mi * 16 + lr;
            int s0 = tileS + wn * 64 + ni * 16 + lq * 4;
            half4 h;
#pragma unroll
            for (int r = 0; r < 4; ++r)
                h[r] = (s0 + r <= tt) ? (_Float16)(acc[mi][ni][r] * scale)
                                      : (_Float16)0.f;
            *(half4*)(S + ((size_t)b * 2048 + tt) * 2048 + s0) = h;
        }
}

// ---------------------------------------------------------------------------
// Softmax: one wave per row, half8 loads, 64-lane shuffle reduce, no LDS.
// R10: skip fully-masked 512-chunks (j > t>>9). Safe: PV reads row t only
// for s < kEnd = (t/128+1)*128 <= (t/512+1)*512, i.e. never past chunk
// t>>9; skipped chunks are never consumed. Branch is wave-uniform (t is
// per-wave), loop statically unrolled so x[] stays in registers.
// ---------------------------------------------------------------------------
__global__ __launch_bounds__(256) void softmax_k(_Float16* __restrict__ S)
{
    const int w    = threadIdx.x >> 6;
    const int lane = threadIdx.x & 63;
    const int t    = blockIdx.x * 4 + w;
    const int b    = blockIdx.y;
    _Float16* row = S + ((size_t)b * 2048 + t) * 2048;
    const int jmax = t >> 9;       // last chunk containing s <= t

    float x[32];
    float mx = -1e30f;
#pragma unroll
    for (int j = 0; j < 4; ++j) {
        if (j <= jmax) {
            half8 h = *(const half8*)(row + j * 512 + lane * 8);
#pragma unroll
            for (int e = 0; e < 8; ++e) {
                int s = j * 512 + lane * 8 + e;
                float f = (s <= t) ? (float)h[e] : -1e30f;
                x[j * 8 + e] = f;
                mx = fmaxf(mx, f);
            }
        }
    }
#pragma unroll
    for (int o = 32; o > 0; o >>= 1) mx = fmaxf(mx, __shfl_xor(mx, o));

    float sum = 0.f;
#pragma unroll
    for (int j = 0; j < 4; ++j) {
        if (j <= jmax) {
#pragma unroll
            for (int e = 0; e < 8; ++e) {
                float ex = __expf(x[j * 8 + e] - mx);   // masked -> 0
                x[j * 8 + e] = ex;
                sum += ex;
            }
        }
    }
#pragma unroll
    for (int o = 32; o > 0; o >>= 1) sum += __shfl_xor(sum, o);
    const float inv = 1.0f / sum;

#pragma unroll
    for (int j = 0; j < 4; ++j) {
        if (j <= jmax) {
            half8 p;
#pragma unroll
            for (int e = 0; e < 8; ++e) p[e] = (_Float16)(x[j * 8 + e] * inv);
            *(half8*)(row + j * 512 + lane * 8) = p;
        }
    }
}

// ---------------------------------------------------------------------------
// PV: 128(t) x 64(d) tiles -> grid (16,16,4) = 1024 blocks, kEnd = tileT+128.
// Longest t-tiles first. Swapped MFMA -> float4 along d.
// ---------------------------------------------------------------------------
__global__ __launch_bounds__(256) void pv_gemm_k(
    const _Float16* __restrict__ P, const _Float16* __restrict__ Vt,
    float* __restrict__ out)
{
    __shared__ __align__(16) _Float16 ldsA[128 * 64];
    __shared__ __align__(16) _Float16 ldsB[64 * 64];
    const int tileT = (15 - blockIdx.x) * 128;   // longest-first
    const int tileD = blockIdx.y * 64;
    const int b     = blockIdx.z;
    const int kEnd  = tileT + 128;

    f32x4 acc[4][2] = {};
    gemm_nt_core<128, 64, 2, 2, true>(
        P + ((size_t)b * 2048 + tileT) * 2048,
        Vt + (size_t)b * 1024 * 2048 + (size_t)tileD * 2048,
        2048, 2048, 0, kEnd, ldsA, ldsB, acc);

    const int lane = threadIdx.x & 63;
    const int w    = threadIdx.x >> 6;
    const int wm = w & 1, wn = w >> 1;
    const int lr = lane & 15, lq = lane >> 4;

#pragma unroll
    for (int mi = 0; mi < 4; ++mi)
#pragma unroll
        for (int ni = 0; ni < 2; ++ni) {
            int tt = tileT + wm * 64 + mi * 16 + lr;
            int d0 = tileD + wn * 32 + ni * 16 + lq * 4;
            *(f32x4*)(out + ((size_t)b * 2048 + tt) * 1024 + d0) = acc[mi][ni];
        }
}

// ---------------------------------------------------------------------------
extern "C" void kernel_launch(void* const* d_in, const int* in_sizes, int n_in,
                              void* d_out, int out_size, void* d_ws, size_t ws_size,
                              hipStream_t stream)
{
    const float* x  = (const float*)d_in[0];
    const float* Wq = (const float*)d_in[1];
    const float* Wk = (const float*)d_in[2];
    const float* Wv = (const float*)d_in[3];
    float* out = (float*)d_out;

    char* ws = (char*)d_ws;
    // layout (MB): xh 0..16 | Wh 16..22 | Q 22..38 | K 38..54 | Vt 54..70 |
    // S16 70..102 (P aliases S).  Total 102 MB.
    _Float16* xh = (_Float16*)(ws);
    _Float16* Wh = (_Float16*)(ws + (16u << 20));
    _Float16* Qh = (_Float16*)(ws + (22u << 20));
    _Float16* Kh = (_Float16*)(ws + (38u << 20));
    _Float16* Vt = (_Float16*)(ws + (54u << 20));
    _Float16* S  = (_Float16*)(ws + (70u << 20));

    f32tof16_k<<<8192, 256, 0, stream>>>(x, xh, 4 * 2048 * 1024);
    wconv_k<<<dim3(1024, 3), 256, 0, stream>>>(Wq, Wk, Wv, Wh);

    qkv_gemm256_k<<<dim3(32, 8, 3), 512, 0, stream>>>(xh, Wh, Qh, Kh, Vt);

    scores_gemm_k<<<dim3(16, 16, 4), 256, 0, stream>>>(Qh, Kh, S);
    softmax_k<<<dim3(512, 4), 256, 0, stream>>>(S);
    pv_gemm_k<<<dim3(16, 16, 4), 256, 0, stream>>>(S, Vt, out);
}